// Round 1
// baseline (2341.349 us; speedup 1.0000x reference)
//
#include <hip/hip_runtime.h>
#include <hip/hip_bf16.h>
#include <math.h>

// Problem constants
#define B_  32
#define S_  512
#define H_  768
#define W_  128
#define G_  4
#define LW  129          // W+1
#define NH_ 4
#define HD_ 192
#define FF_ 2048
#define NL_ 2
#define NLAB_ 6
#define M_  (B_ * LW)    // 4128 rows of x
#define EPS_ 1e-5f
#define NEG_ -3.4028235e38f
#define SCALE_ 0.07216878364870323f   // 1/sqrt(192)

// ---------------- reductions (256-thread blocks = 4 waves) ----------------
__device__ __forceinline__ float wave_sum(float v) {
#pragma unroll
    for (int off = 1; off < 64; off <<= 1) v += __shfl_xor(v, off, 64);
    return v;
}
__device__ __forceinline__ float wave_max(float v) {
#pragma unroll
    for (int off = 1; off < 64; off <<= 1) v = fmaxf(v, __shfl_xor(v, off, 64));
    return v;
}
__device__ __forceinline__ float block_sum(float v, float* red) {
    v = wave_sum(v);
    int wid = threadIdx.x >> 6, lane = threadIdx.x & 63;
    if (lane == 0) red[wid] = v;
    __syncthreads();
    float r = (red[0] + red[1]) + (red[2] + red[3]);
    __syncthreads();
    return r;
}
__device__ __forceinline__ float block_max(float v, float* red) {
    v = wave_max(v);
    int wid = threadIdx.x >> 6, lane = threadIdx.x & 63;
    if (lane == 0) red[wid] = v;
    __syncthreads();
    float r = fmaxf(fmaxf(red[0], red[1]), fmaxf(red[2], red[3]));
    __syncthreads();
    return r;
}

// ---------------- gather + masked mean pool -> x (M_, H_) ----------------
__global__ __launch_bounds__(256) void build_x_kernel(
    const float* __restrict__ hidden,   // (B,S,H)
    const int*   __restrict__ wti,      // (B,W,G)
    const int*   __restrict__ gmask,    // (B,W,G) bool as int32
    const int*   __restrict__ wvalid,   // (B,W)   bool as int32
    float* __restrict__ x)              // (B,LW,H)
{
    int t = blockIdx.x;     // 0..LW-1
    int b = blockIdx.y;     // 0..B-1
    int tid = threadIdx.x;
    size_t xo = ((size_t)b * LW + t) * H_;
    if (t == 0) {
        const float* src = hidden + (size_t)b * S_ * H_;   // token 0
#pragma unroll
        for (int i = 0; i < 3; i++) x[xo + tid + i * 256] = src[tid + i * 256];
    } else {
        int w = t - 1;
        int valid = wvalid[b * W_ + w];
        int ids[G_]; float msk[G_]; float cnt = 0.f;
#pragma unroll
        for (int g = 0; g < G_; g++) {
            ids[g] = wti[(b * W_ + w) * G_ + g];
            msk[g] = (gmask[(b * W_ + w) * G_ + g] != 0) ? 1.f : 0.f;
            cnt += msk[g];
        }
        float inv = valid ? (1.f / fmaxf(cnt, 1.f)) : 0.f;
#pragma unroll
        for (int i = 0; i < 3; i++) {
            int c = tid + i * 256;
            float a = 0.f;
#pragma unroll
            for (int g = 0; g < G_; g++)
                a += msk[g] * hidden[((size_t)b * S_ + ids[g]) * H_ + c];
            x[xo + c] = a * inv;
        }
    }
}

// ---------------- fp32 tiled GEMM: C(M,N) = A(M,K) @ Bw(N,K)^T + bias ----------------
// 64x64 tile, BK=16, 256 threads, 4x4 microtile per thread.
__global__ __launch_bounds__(256) void gemm_bt(
    const float* __restrict__ A,
    const float* __restrict__ Bw,
    const float* __restrict__ bias,
    float* __restrict__ C,
    int M, int N, int K, int relu)
{
    __shared__ __align__(16) float As[16][68];
    __shared__ __align__(16) float Bs[16][68];
    int tid = threadIdx.x;
    int tx = tid & 15;          // 0..15
    int ty = tid >> 4;          // 0..15
    int block_m = blockIdx.y * 64;
    int block_n = blockIdx.x * 64;

    float acc[4][4] = {};

    for (int k0 = 0; k0 < K; k0 += 16) {
#pragma unroll
        for (int i = 0; i < 4; i++) {
            int r = ty + i * 16;           // 0..63
            int gm = block_m + r;
            float av = (gm < M) ? A[(size_t)gm * K + k0 + tx] : 0.f;
            As[tx][r] = av;
            int gn = block_n + r;          // N is always a multiple of 64
            Bs[tx][r] = Bw[(size_t)gn * K + k0 + tx];
        }
        __syncthreads();
#pragma unroll
        for (int k = 0; k < 16; k++) {
            float4 a = *reinterpret_cast<const float4*>(&As[k][ty * 4]);
            float4 bq = *reinterpret_cast<const float4*>(&Bs[k][tx * 4]);
            acc[0][0] += a.x * bq.x; acc[0][1] += a.x * bq.y; acc[0][2] += a.x * bq.z; acc[0][3] += a.x * bq.w;
            acc[1][0] += a.y * bq.x; acc[1][1] += a.y * bq.y; acc[1][2] += a.y * bq.z; acc[1][3] += a.y * bq.w;
            acc[2][0] += a.z * bq.x; acc[2][1] += a.z * bq.y; acc[2][2] += a.z * bq.z; acc[2][3] += a.z * bq.w;
            acc[3][0] += a.w * bq.x; acc[3][1] += a.w * bq.y; acc[3][2] += a.w * bq.z; acc[3][3] += a.w * bq.w;
        }
        __syncthreads();
    }
#pragma unroll
    for (int i = 0; i < 4; i++) {
        int gm = block_m + ty * 4 + i;
        if (gm >= M) continue;
#pragma unroll
        for (int j = 0; j < 4; j++) {
            int gn = block_n + tx * 4 + j;
            float v = acc[i][j] + bias[gn];
            if (relu) v = fmaxf(v, 0.f);
            C[(size_t)gm * N + gn] = v;
        }
    }
}

// ---------------- attention: one block per (q, h, b) ----------------
__global__ __launch_bounds__(256) void attn_kernel(
    const float* __restrict__ qkv,     // (M_, 3*H_): [q | k | v]
    const int*   __restrict__ wvalid,  // (B,W)
    float* __restrict__ ctx)           // (M_, H_)
{
    int q = blockIdx.x;   // 0..LW-1
    int h = blockIdx.y;   // 0..NH-1
    int b = blockIdx.z;   // 0..B-1
    int tid = threadIdx.x;

    __shared__ float qs[HD_];
    __shared__ float ps[LW];
    __shared__ float red[4];

    size_t base = (size_t)b * LW * (3 * H_);
    if (tid < HD_) qs[tid] = qkv[base + (size_t)q * (3 * H_) + h * HD_ + tid];
    __syncthreads();

    float s = NEG_;
    if (tid < LW) {
        const float* kv = &qkv[base + (size_t)tid * (3 * H_) + H_ + h * HD_];
        float acc = 0.f;
        for (int d = 0; d < HD_; d++) acc += qs[d] * kv[d];
        bool pad = (tid > 0) && (wvalid[b * W_ + (tid - 1)] == 0);
        s = pad ? NEG_ : acc * SCALE_;
    }
    float m = block_max(s, red);
    float e = (tid < LW) ? expf(s - m) : 0.f;
    float sum = block_sum(e, red);
    if (tid < LW) ps[tid] = e / sum;
    __syncthreads();

    if (tid < HD_) {
        float acc = 0.f;
        for (int k = 0; k < LW; k++)
            acc += ps[k] * qkv[base + (size_t)k * (3 * H_) + 2 * H_ + h * HD_ + tid];
        ctx[((size_t)b * LW + q) * H_ + h * HD_ + tid] = acc;
    }
}

// ---------------- fused residual add + LayerNorm (in place on x) ----------------
__global__ __launch_bounds__(256) void add_ln_kernel(
    float* __restrict__ x, const float* __restrict__ res,
    const float* __restrict__ sc, const float* __restrict__ bi)
{
    __shared__ float red[4];
    int row = blockIdx.x;
    int tid = threadIdx.x;
    size_t base = (size_t)row * H_;
    float v[3];
    float sum = 0.f;
#pragma unroll
    for (int i = 0; i < 3; i++) {
        int c = tid + i * 256;
        float t = x[base + c] + res[base + c];
        v[i] = t; sum += t;
    }
    sum = block_sum(sum, red);
    float mean = sum * (1.f / H_);
    float var = 0.f;
#pragma unroll
    for (int i = 0; i < 3; i++) { float d = v[i] - mean; var += d * d; }
    var = block_sum(var, red);
    float inv = rsqrtf(var * (1.f / H_) + EPS_);
#pragma unroll
    for (int i = 0; i < 3; i++) {
        int c = tid + i * 256;
        x[base + c] = (v[i] - mean) * inv * sc[c] + bi[c];
    }
}

// ---------------- classifier + pooled copy ----------------
__global__ __launch_bounds__(256) void cls_kernel(
    const float* __restrict__ x,
    const float* __restrict__ cls_w, const float* __restrict__ cls_b,
    float* __restrict__ out)
{
    int tid = threadIdx.x;
    // pooled copy: out[B*NLAB + b*H + c] = x[b*LW*H + c]
    for (int i = tid; i < B_ * H_; i += 256) {
        int b = i / H_, c = i % H_;
        out[B_ * NLAB_ + i] = x[((size_t)b * LW) * H_ + c];
    }
    if (tid < B_ * NLAB_) {
        int b = tid / NLAB_, lab = tid % NLAB_;
        float acc = cls_b[lab];
        const float* p = &x[((size_t)b * LW) * H_];
        const float* wv = &cls_w[lab * H_];
        for (int c = 0; c < H_; c++) acc += p[c] * wv[c];
        out[b * NLAB_ + lab] = acc;
    }
}

extern "C" void kernel_launch(void* const* d_in, const int* in_sizes, int n_in,
                              void* d_out, int out_size, void* d_ws, size_t ws_size,
                              hipStream_t stream) {
    const float* hidden = (const float*)d_in[0];
    const int*   wti    = (const int*)d_in[1];
    const int*   gmask  = (const int*)d_in[2];
    const int*   wvalid = (const int*)d_in[3];
    const float* qkv_w  = (const float*)d_in[4];
    const float* qkv_b  = (const float*)d_in[5];
    const float* out_w  = (const float*)d_in[6];
    const float* out_b  = (const float*)d_in[7];
    const float* ff1_w  = (const float*)d_in[8];
    const float* ff1_b  = (const float*)d_in[9];
    const float* ff2_w  = (const float*)d_in[10];
    const float* ff2_b  = (const float*)d_in[11];
    const float* ln1_s  = (const float*)d_in[12];
    const float* ln1_b  = (const float*)d_in[13];
    const float* ln2_s  = (const float*)d_in[14];
    const float* ln2_b  = (const float*)d_in[15];
    const float* cls_w  = (const float*)d_in[16];
    const float* cls_b  = (const float*)d_in[17];
    float* out = (float*)d_out;

    float* ws  = (float*)d_ws;
    float* x   = ws;                          // M_*H_
    float* big = x   + (size_t)M_ * H_;       // M_*3H_ (qkv; also reused for h1 M_*FF_)
    float* ctx = big + (size_t)M_ * 3 * H_;   // M_*H_
    float* tmp = ctx + (size_t)M_ * H_;       // M_*H_

    build_x_kernel<<<dim3(LW, B_), 256, 0, stream>>>(hidden, wti, gmask, wvalid, x);

    const int gy = (M_ + 63) / 64;   // 65
    for (int l = 0; l < NL_; l++) {
        // qkv = x @ qkv_w^T + qkv_b
        gemm_bt<<<dim3(3 * H_ / 64, gy), 256, 0, stream>>>(
            x, qkv_w + (size_t)l * 3 * H_ * H_, qkv_b + (size_t)l * 3 * H_,
            big, M_, 3 * H_, H_, 0);
        // attention
        attn_kernel<<<dim3(LW, NH_, B_), 256, 0, stream>>>(big, wvalid, ctx);
        // attn out-proj
        gemm_bt<<<dim3(H_ / 64, gy), 256, 0, stream>>>(
            ctx, out_w + (size_t)l * H_ * H_, out_b + (size_t)l * H_,
            tmp, M_, H_, H_, 0);
        // x = LN(x + attn)
        add_ln_kernel<<<M_, 256, 0, stream>>>(x, tmp, ln1_s + (size_t)l * H_, ln1_b + (size_t)l * H_);
        // h1 = relu(x @ ff1_w^T + ff1_b)
        gemm_bt<<<dim3(FF_ / 64, gy), 256, 0, stream>>>(
            x, ff1_w + (size_t)l * FF_ * H_, ff1_b + (size_t)l * FF_,
            big, M_, FF_, H_, 1);
        // ff = h1 @ ff2_w^T + ff2_b
        gemm_bt<<<dim3(H_ / 64, gy), 256, 0, stream>>>(
            big, ff2_w + (size_t)l * H_ * FF_, ff2_b + (size_t)l * H_,
            tmp, M_, H_, FF_, 0);
        // x = LN(x + ff)
        add_ln_kernel<<<M_, 256, 0, stream>>>(x, tmp, ln2_s + (size_t)l * H_, ln2_b + (size_t)l * H_);
    }
    cls_kernel<<<1, 256, 0, stream>>>(x, cls_w, cls_b, out);
}

// Round 2
// 831.889 us; speedup vs baseline: 2.8145x; 2.8145x over previous
//
#include <hip/hip_runtime.h>
#include <hip/hip_bf16.h>
#include <math.h>

// Problem constants
#define B_  32
#define S_  512
#define H_  768
#define W_  128
#define G_  4
#define LW  129          // W+1
#define NH_ 4
#define HD_ 192
#define FF_ 2048
#define NL_ 2
#define NLAB_ 6
#define M_   (B_ * LW)   // 4128 rows of x
#define MPAD 4224        // 33 * 128 — zero GEMM bounds checks
#define EPS_ 1e-5f
#define NEG_ -3.4028235e38f
#define SCALE_ 0.07216878364870323f   // 1/sqrt(192)

#define QW_SZ (3 * H_ * H_)   // 1769472
#define OW_SZ (H_ * H_)       // 589824
#define F1_SZ (FF_ * H_)      // 1572864
#define F2_SZ (H_ * FF_)      // 1572864
#define WL_SZ (QW_SZ + OW_SZ + F1_SZ + F2_SZ)  // 5505024

typedef __bf16 bf16_8 __attribute__((ext_vector_type(8)));
typedef float  f32x4  __attribute__((ext_vector_type(4)));

__device__ __forceinline__ float b2f(unsigned short u) {
    union { unsigned int i; float f; } c; c.i = ((unsigned int)u) << 16; return c.f;
}
__device__ __forceinline__ unsigned short f2b(float f) {
    union { float f; unsigned int u; } c; c.f = f;
    unsigned int u = c.u;
    return (unsigned short)((u + 0x7FFFu + ((u >> 16) & 1u)) >> 16);   // RNE
}

// ---------------- reductions (256-thread blocks = 4 waves) ----------------
__device__ __forceinline__ float wave_sum(float v) {
#pragma unroll
    for (int off = 1; off < 64; off <<= 1) v += __shfl_xor(v, off, 64);
    return v;
}
__device__ __forceinline__ float wave_max(float v) {
#pragma unroll
    for (int off = 1; off < 64; off <<= 1) v = fmaxf(v, __shfl_xor(v, off, 64));
    return v;
}
__device__ __forceinline__ float block_sum(float v, float* red) {
    v = wave_sum(v);
    int wid = threadIdx.x >> 6, lane = threadIdx.x & 63;
    if (lane == 0) red[wid] = v;
    __syncthreads();
    float r = (red[0] + red[1]) + (red[2] + red[3]);
    __syncthreads();
    return r;
}
__device__ __forceinline__ float block_max(float v, float* red) {
    v = wave_max(v);
    int wid = threadIdx.x >> 6, lane = threadIdx.x & 63;
    if (lane == 0) red[wid] = v;
    __syncthreads();
    float r = fmaxf(fmaxf(red[0], red[1]), fmaxf(red[2], red[3]));
    __syncthreads();
    return r;
}

// ---------------- gather + masked mean pool -> x (f32 + bf16) ----------------
__global__ __launch_bounds__(256) void build_x_kernel(
    const float* __restrict__ hidden,   // (B,S,H)
    const int*   __restrict__ wti,      // (B,W,G)
    const int*   __restrict__ gmask,    // (B,W,G) bool as int32
    const int*   __restrict__ wvalid,   // (B,W)   bool as int32
    float* __restrict__ x,              // (MPAD,H) f32 (valid rows only)
    unsigned short* __restrict__ xb)    // (MPAD,H) bf16
{
    int t = blockIdx.x;     // 0..LW-1
    int b = blockIdx.y;     // 0..B-1
    int tid = threadIdx.x;
    size_t xo = ((size_t)b * LW + t) * H_;
    if (t == 0) {
        const float* src = hidden + (size_t)b * S_ * H_;   // token 0
#pragma unroll
        for (int i = 0; i < 3; i++) {
            float v = src[tid + i * 256];
            x[xo + tid + i * 256] = v;
            xb[xo + tid + i * 256] = f2b(v);
        }
    } else {
        int w = t - 1;
        int valid = wvalid[b * W_ + w];
        int ids[G_]; float msk[G_]; float cnt = 0.f;
#pragma unroll
        for (int g = 0; g < G_; g++) {
            ids[g] = wti[(b * W_ + w) * G_ + g];
            msk[g] = (gmask[(b * W_ + w) * G_ + g] != 0) ? 1.f : 0.f;
            cnt += msk[g];
        }
        float inv = valid ? (1.f / fmaxf(cnt, 1.f)) : 0.f;
#pragma unroll
        for (int i = 0; i < 3; i++) {
            int c = tid + i * 256;
            float a = 0.f;
#pragma unroll
            for (int g = 0; g < G_; g++)
                a += msk[g] * hidden[((size_t)b * S_ + ids[g]) * H_ + c];
            float v = a * inv;
            x[xo + c] = v;
            xb[xo + c] = f2b(v);
        }
    }
}

__global__ __launch_bounds__(256) void zero_pad_xb(unsigned short* __restrict__ xb) {
    int i = blockIdx.x * 256 + threadIdx.x;        // (MPAD-M_)*H_ = 73728
    if (i < (MPAD - M_) * H_) xb[(size_t)M_ * H_ + i] = 0;
}

// ---------------- weight fp32 -> bf16 (one layer, 4 matrices fused) ----------------
__global__ __launch_bounds__(256) void cvt_layer_kernel(
    const float4* __restrict__ qw, const float4* __restrict__ ow,
    const float4* __restrict__ f1, const float4* __restrict__ f2,
    ushort4* __restrict__ dst)
{
    int i = blockIdx.x * 256 + threadIdx.x;   // float4 units; WL_SZ/4 = 1376256 total
    float4 v;
    if (i < QW_SZ / 4)                          v = qw[i];
    else if (i < (QW_SZ + OW_SZ) / 4)           v = ow[i - QW_SZ / 4];
    else if (i < (QW_SZ + OW_SZ + F1_SZ) / 4)   v = f1[i - (QW_SZ + OW_SZ) / 4];
    else                                        v = f2[i - (QW_SZ + OW_SZ + F1_SZ) / 4];
    ushort4 o; o.x = f2b(v.x); o.y = f2b(v.y); o.z = f2b(v.z); o.w = f2b(v.w);
    dst[i] = o;
}

// ---------------- bf16 MFMA GEMM: C(MPAD,N) = A(MPAD,K) @ Bw(N,K)^T + bias ----------------
// m97 ladder structure: 128xBN tile, BK=32, 4 waves (2x2), global_load_lds width=16,
// row-major unpadded LDS (required: global_load_lds dest is wave-uniform base + lane*16).
template <int BN, int RELU, int OUTBF>
__global__ __launch_bounds__(256) void gemm_mfma(
    const unsigned short* __restrict__ A,   // (MPAD,K) bf16
    const unsigned short* __restrict__ Bw,  // (N,K) bf16
    const float* __restrict__ bias,         // (N) f32
    void* __restrict__ Cout,                // (MPAD,N) f32 or bf16
    int N, int K)
{
    constexpr int NT = BN / 32;             // n-tiles per wave: 4 (BN=128) or 2 (BN=64)
    __shared__ __align__(16) unsigned short As[128 * 32];
    __shared__ __align__(16) unsigned short Bs[BN * 32];

    const int tid  = threadIdx.x;
    const int lane = tid & 63;
    const int wid  = tid >> 6;
    const int bm = blockIdx.y * 128;
    const int bn = blockIdx.x * BN;

    const int wm = (wid & 1) * 64;          // wave m-offset
    const int wn = (wid >> 1) * (BN / 2);   // wave n-offset
    const int r  = lane & 15;
    const int ko = (lane >> 4) * 8;         // k-offset (elements)

    // staging source pointers: thread t -> row t/4, 16B chunk t%4 (row-major, 64B rows)
    const unsigned short* Ag = A  + (size_t)(bm + (tid >> 2)) * K + (tid & 3) * 8;
    const unsigned short* Bg = Bw + (size_t)(bn + (tid >> 2)) * K + (tid & 3) * 8;

    // fragment LDS indices (invariant across K-loop)
    const bf16_8* Af = (const bf16_8*)As;
    const bf16_8* Bf = (const bf16_8*)Bs;
    int ai[4], bi[NT];
#pragma unroll
    for (int i = 0; i < 4; i++) ai[i] = ((wm + i * 16 + r) * 32 + ko) >> 3;
#pragma unroll
    for (int j = 0; j < NT; j++) bi[j] = ((wn + j * 16 + r) * 32 + ko) >> 3;

    f32x4 acc[4][NT];
#pragma unroll
    for (int i = 0; i < 4; i++)
#pragma unroll
        for (int j = 0; j < NT; j++) acc[i][j] = (f32x4){0.f, 0.f, 0.f, 0.f};

    for (int k0 = 0; k0 < K; k0 += 32) {
        __builtin_amdgcn_global_load_lds(
            (const __attribute__((address_space(1))) void*)(Ag + k0),
            (__attribute__((address_space(3))) void*)(As + tid * 8), 16, 0, 0);
        __builtin_amdgcn_global_load_lds(
            (const __attribute__((address_space(1))) void*)(Ag + (size_t)64 * K + k0),
            (__attribute__((address_space(3))) void*)(As + 2048 + tid * 8), 16, 0, 0);
        __builtin_amdgcn_global_load_lds(
            (const __attribute__((address_space(1))) void*)(Bg + k0),
            (__attribute__((address_space(3))) void*)(Bs + tid * 8), 16, 0, 0);
        if constexpr (BN == 128)
            __builtin_amdgcn_global_load_lds(
                (const __attribute__((address_space(1))) void*)(Bg + (size_t)64 * K + k0),
                (__attribute__((address_space(3))) void*)(Bs + 2048 + tid * 8), 16, 0, 0);
        __syncthreads();   // compiler emits vmcnt(0) drain before s_barrier -> LDS ready

        bf16_8 a[4], b[NT];
#pragma unroll
        for (int i = 0; i < 4; i++) a[i] = Af[ai[i]];
#pragma unroll
        for (int j = 0; j < NT; j++) b[j] = Bf[bi[j]];
#pragma unroll
        for (int i = 0; i < 4; i++)
#pragma unroll
            for (int j = 0; j < NT; j++)
                acc[i][j] = __builtin_amdgcn_mfma_f32_16x16x32_bf16(a[i], b[j], acc[i][j], 0, 0, 0);
        __syncthreads();
    }

    // epilogue: C/D layout col=lane&15, row=(lane>>4)*4+reg  [m89/m91 verified]
    int col[NT]; float bv[NT];
#pragma unroll
    for (int j = 0; j < NT; j++) { col[j] = bn + wn + j * 16 + r; bv[j] = bias[col[j]]; }
    const int row0 = bm + wm + ((lane >> 4) << 2);
#pragma unroll
    for (int i = 0; i < 4; i++) {
#pragma unroll
        for (int rg = 0; rg < 4; rg++) {
            size_t rowoff = (size_t)(row0 + i * 16 + rg) * N;
#pragma unroll
            for (int j = 0; j < NT; j++) {
                float v = acc[i][j][rg] + bv[j];
                if (RELU) v = fmaxf(v, 0.f);
                if (OUTBF) ((unsigned short*)Cout)[rowoff + col[j]] = f2b(v);
                else       ((float*)Cout)[rowoff + col[j]] = v;
            }
        }
    }
}

// ---------------- attention: one block per (q, h, b), bf16 qkv ----------------
__global__ __launch_bounds__(256) void attn_kernel(
    const unsigned short* __restrict__ qkv,   // (MPAD, 3H) bf16: [q|k|v]
    const int*            __restrict__ wvalid,
    unsigned short*       __restrict__ ctx)   // (MPAD, H) bf16
{
    int q = blockIdx.x;   // 0..LW-1
    int h = blockIdx.y;   // 0..NH-1
    int b = blockIdx.z;   // 0..B-1
    int tid = threadIdx.x;

    __shared__ float qs[HD_];
    __shared__ float ps[LW];
    __shared__ float red[4];

    size_t base = (size_t)b * LW * (3 * H_);
    if (tid < HD_) qs[tid] = b2f(qkv[base + (size_t)q * (3 * H_) + h * HD_ + tid]);
    __syncthreads();

    float s = NEG_;
    if (tid < LW) {
        const ushort4* kv4 = (const ushort4*)(qkv + base + (size_t)tid * (3 * H_) + H_ + h * HD_);
        float acc = 0.f;
#pragma unroll 4
        for (int d4 = 0; d4 < HD_ / 4; d4++) {
            ushort4 t = kv4[d4];
            acc += qs[4 * d4] * b2f(t.x) + qs[4 * d4 + 1] * b2f(t.y)
                 + qs[4 * d4 + 2] * b2f(t.z) + qs[4 * d4 + 3] * b2f(t.w);
        }
        bool pad = (tid > 0) && (wvalid[b * W_ + (tid - 1)] == 0);
        s = pad ? NEG_ : acc * SCALE_;
    }
    float m = block_max(s, red);
    float e = (tid < LW) ? expf(s - m) : 0.f;
    float sum = block_sum(e, red);
    if (tid < LW) ps[tid] = e / sum;
    __syncthreads();

    if (tid < HD_) {
        float acc = 0.f;
        for (int k = 0; k < LW; k++)
            acc += ps[k] * b2f(qkv[base + (size_t)k * (3 * H_) + 2 * H_ + h * HD_ + tid]);
        ctx[((size_t)b * LW + q) * H_ + h * HD_ + tid] = f2b(acc);
    }
}

// ---------------- fused residual add + LayerNorm (x32 master, bf16 mirror) ----------------
__global__ __launch_bounds__(256) void add_ln_kernel(
    float* __restrict__ x, const float* __restrict__ res,
    const float* __restrict__ sc, const float* __restrict__ bi,
    unsigned short* __restrict__ xb)
{
    __shared__ float red[4];
    int row = blockIdx.x;
    int tid = threadIdx.x;
    size_t base = (size_t)row * H_;
    float v[3];
    float sum = 0.f;
#pragma unroll
    for (int i = 0; i < 3; i++) {
        int c = tid + i * 256;
        float t = x[base + c] + res[base + c];
        v[i] = t; sum += t;
    }
    sum = block_sum(sum, red);
    float mean = sum * (1.f / H_);
    float var = 0.f;
#pragma unroll
    for (int i = 0; i < 3; i++) { float d = v[i] - mean; var += d * d; }
    var = block_sum(var, red);
    float inv = rsqrtf(var * (1.f / H_) + EPS_);
#pragma unroll
    for (int i = 0; i < 3; i++) {
        int c = tid + i * 256;
        float r = (v[i] - mean) * inv * sc[c] + bi[c];
        x[base + c] = r;
        xb[base + c] = f2b(r);
    }
}

// ---------------- classifier + pooled copy (pure fp32) ----------------
__global__ __launch_bounds__(256) void cls_kernel(
    const float* __restrict__ x,
    const float* __restrict__ cls_w, const float* __restrict__ cls_b,
    float* __restrict__ out)
{
    int tid = threadIdx.x;
    for (int i = tid; i < B_ * H_; i += 256) {
        int b = i / H_, c = i % H_;
        out[B_ * NLAB_ + i] = x[((size_t)b * LW) * H_ + c];
    }
    if (tid < B_ * NLAB_) {
        int b = tid / NLAB_, lab = tid % NLAB_;
        float acc = cls_b[lab];
        const float* p = &x[((size_t)b * LW) * H_];
        const float* wv = &cls_w[lab * H_];
        for (int c = 0; c < H_; c++) acc += p[c] * wv[c];
        out[b * NLAB_ + lab] = acc;
    }
}

extern "C" void kernel_launch(void* const* d_in, const int* in_sizes, int n_in,
                              void* d_out, int out_size, void* d_ws, size_t ws_size,
                              hipStream_t stream) {
    const float* hidden = (const float*)d_in[0];
    const int*   wti    = (const int*)d_in[1];
    const int*   gmask  = (const int*)d_in[2];
    const int*   wvalid = (const int*)d_in[3];
    const float* qkv_w  = (const float*)d_in[4];
    const float* qkv_b  = (const float*)d_in[5];
    const float* out_w  = (const float*)d_in[6];
    const float* out_b  = (const float*)d_in[7];
    const float* ff1_w  = (const float*)d_in[8];
    const float* ff1_b  = (const float*)d_in[9];
    const float* ff2_w  = (const float*)d_in[10];
    const float* ff2_b  = (const float*)d_in[11];
    const float* ln1_s  = (const float*)d_in[12];
    const float* ln1_b  = (const float*)d_in[13];
    const float* ln2_s  = (const float*)d_in[14];
    const float* ln2_b  = (const float*)d_in[15];
    const float* cls_w  = (const float*)d_in[16];
    const float* cls_b  = (const float*)d_in[17];
    float* out = (float*)d_out;

    // workspace: 69.4 MB total (proven >= 76.1 MB available in R1)
    float* x32   = (float*)d_ws;                              // MPAD*H f32
    float* tmp32 = x32 + (size_t)MPAD * H_;                   // MPAD*H f32
    unsigned short* xb   = (unsigned short*)(tmp32 + (size_t)MPAD * H_);  // MPAD*H bf16
    unsigned short* ctxb = xb + (size_t)MPAD * H_;            // MPAD*H bf16
    unsigned short* qkvb = ctxb + (size_t)MPAD * H_;          // MPAD*3H bf16 (aliased: h1b MPAD*FF)
    unsigned short* wb   = qkvb + (size_t)MPAD * 3 * H_;      // WL_SZ bf16 (one layer's weights)

    build_x_kernel<<<dim3(LW, B_), 256, 0, stream>>>(hidden, wti, gmask, wvalid, x32, xb);
    zero_pad_xb<<<288, 256, 0, stream>>>(xb);

    const dim3 g128(0, MPAD / 128);   // y = 33
    for (int l = 0; l < NL_; l++) {
        cvt_layer_kernel<<<WL_SZ / 4 / 256, 256, 0, stream>>>(
            (const float4*)(qkv_w + (size_t)l * QW_SZ), (const float4*)(out_w + (size_t)l * OW_SZ),
            (const float4*)(ff1_w + (size_t)l * F1_SZ), (const float4*)(ff2_w + (size_t)l * F2_SZ),
            (ushort4*)wb);
        // qkv = x @ qkv_w^T + b  -> bf16
        gemm_mfma<128, 0, 1><<<dim3(3 * H_ / 128, MPAD / 128), 256, 0, stream>>>(
            xb, wb, qkv_b + (size_t)l * 3 * H_, qkvb, 3 * H_, H_);
        attn_kernel<<<dim3(LW, NH_, B_), 256, 0, stream>>>(qkvb, wvalid, ctxb);
        // attn out-proj -> f32 tmp
        gemm_mfma<64, 0, 0><<<dim3(H_ / 64, MPAD / 128), 256, 0, stream>>>(
            ctxb, wb + QW_SZ, out_b + (size_t)l * H_, tmp32, H_, H_);
        add_ln_kernel<<<M_, 256, 0, stream>>>(x32, tmp32,
            ln1_s + (size_t)l * H_, ln1_b + (size_t)l * H_, xb);
        // h1 = relu(x @ ff1_w^T + b) -> bf16 (into qkvb region)
        gemm_mfma<128, 1, 1><<<dim3(FF_ / 128, MPAD / 128), 256, 0, stream>>>(
            xb, wb + QW_SZ + OW_SZ, ff1_b + (size_t)l * FF_, qkvb, FF_, H_);
        // ff2 -> f32 tmp
        gemm_mfma<64, 0, 0><<<dim3(H_ / 64, MPAD / 128), 256, 0, stream>>>(
            qkvb, wb + QW_SZ + OW_SZ + F1_SZ, ff2_b + (size_t)l * H_, tmp32, H_, FF_);
        add_ln_kernel<<<M_, 256, 0, stream>>>(x32, tmp32,
            ln2_s + (size_t)l * H_, ln2_b + (size_t)l * H_, xb);
    }
    cls_kernel<<<1, 256, 0, stream>>>(x32, cls_w, cls_b, out);
    (void)g128; (void)in_sizes; (void)n_in; (void)out_size; (void)ws_size;
}

// Round 3
// 539.368 us; speedup vs baseline: 4.3409x; 1.5423x over previous
//
#include <hip/hip_runtime.h>
#include <hip/hip_bf16.h>
#include <math.h>

// Problem constants
#define B_  32
#define S_  512
#define H_  768
#define W_  128
#define G_  4
#define LW  129          // W+1
#define NH_ 4
#define HD_ 192
#define FF_ 2048
#define NL_ 2
#define NLAB_ 6
#define M_   (B_ * LW)   // 4128 rows of x
#define MPAD 4224        // 33 * 128 — zero GEMM bounds checks
#define EPS_ 1e-5f
#define SCALE_ 0.07216878364870323f   // 1/sqrt(192)

// attention padded dims
#define TP 192           // padded query rows per (b,h)  (3 blocks of 64)
#define KP 160           // padded key count (mult of 32)
#define KR 144           // staged key rows (9 n-tiles)
#define KLD 200          // LDS row stride for K/V stage (bank-friendly)

#define QW_SZ (3 * H_ * H_)   // 1769472
#define OW_SZ (H_ * H_)       // 589824
#define F1_SZ (FF_ * H_)      // 1572864
#define F2_SZ (H_ * FF_)      // 1572864
#define WL_SZ (QW_SZ + OW_SZ + F1_SZ + F2_SZ)  // 5505024

typedef __bf16 bf16_8 __attribute__((ext_vector_type(8)));
typedef float  f32x4  __attribute__((ext_vector_type(4)));
typedef unsigned short ushort8_t __attribute__((ext_vector_type(8)));

__device__ __forceinline__ float b2f(unsigned short u) {
    union { unsigned int i; float f; } c; c.i = ((unsigned int)u) << 16; return c.f;
}
__device__ __forceinline__ unsigned short f2b(float f) {
    union { float f; unsigned int u; } c; c.f = f;
    unsigned int u = c.u;
    return (unsigned short)((u + 0x7FFFu + ((u >> 16) & 1u)) >> 16);   // RNE
}

// ---------------- reductions (256-thread blocks = 4 waves) ----------------
__device__ __forceinline__ float wave_sum(float v) {
#pragma unroll
    for (int off = 1; off < 64; off <<= 1) v += __shfl_xor(v, off, 64);
    return v;
}
__device__ __forceinline__ float block_sum(float v, float* red) {
    v = wave_sum(v);
    int wid = threadIdx.x >> 6, lane = threadIdx.x & 63;
    if (lane == 0) red[wid] = v;
    __syncthreads();
    float r = (red[0] + red[1]) + (red[2] + red[3]);
    __syncthreads();
    return r;
}

// ---------------- gather + masked mean pool -> x (f32 + bf16) ----------------
__global__ __launch_bounds__(256) void build_x_kernel(
    const float* __restrict__ hidden,   // (B,S,H)
    const int*   __restrict__ wti,      // (B,W,G)
    const int*   __restrict__ gmask,    // (B,W,G) bool as int32
    const int*   __restrict__ wvalid,   // (B,W)   bool as int32
    float* __restrict__ x,              // (MPAD,H) f32 (valid rows only)
    unsigned short* __restrict__ xb)    // (MPAD,H) bf16
{
    int t = blockIdx.x;     // 0..LW-1
    int b = blockIdx.y;     // 0..B-1
    int tid = threadIdx.x;
    size_t xo = ((size_t)b * LW + t) * H_;
    if (t == 0) {
        const float* src = hidden + (size_t)b * S_ * H_;   // token 0
#pragma unroll
        for (int i = 0; i < 3; i++) {
            float v = src[tid + i * 256];
            x[xo + tid + i * 256] = v;
            xb[xo + tid + i * 256] = f2b(v);
        }
    } else {
        int w = t - 1;
        int valid = wvalid[b * W_ + w];
        int ids[G_]; float msk[G_]; float cnt = 0.f;
#pragma unroll
        for (int g = 0; g < G_; g++) {
            ids[g] = wti[(b * W_ + w) * G_ + g];
            msk[g] = (gmask[(b * W_ + w) * G_ + g] != 0) ? 1.f : 0.f;
            cnt += msk[g];
        }
        float inv = valid ? (1.f / fmaxf(cnt, 1.f)) : 0.f;
#pragma unroll
        for (int i = 0; i < 3; i++) {
            int c = tid + i * 256;
            float a = 0.f;
#pragma unroll
            for (int g = 0; g < G_; g++)
                a += msk[g] * hidden[((size_t)b * S_ + ids[g]) * H_ + c];
            float v = a * inv;
            x[xo + c] = v;
            xb[xo + c] = f2b(v);
        }
    }
}

__global__ __launch_bounds__(256) void zero_pad_xb(unsigned short* __restrict__ xb) {
    int i = blockIdx.x * 256 + threadIdx.x;        // (MPAD-M_)*H_ = 73728
    if (i < (MPAD - M_) * H_) xb[(size_t)M_ * H_ + i] = 0;
}

// ---------------- weight fp32 -> bf16 (one layer, 4 matrices fused) ----------------
__global__ __launch_bounds__(256) void cvt_layer_kernel(
    const float4* __restrict__ qw, const float4* __restrict__ ow,
    const float4* __restrict__ f1, const float4* __restrict__ f2,
    ushort4* __restrict__ dst)
{
    int i = blockIdx.x * 256 + threadIdx.x;   // float4 units; WL_SZ/4 = 1376256 total
    float4 v;
    if (i < QW_SZ / 4)                          v = qw[i];
    else if (i < (QW_SZ + OW_SZ) / 4)           v = ow[i - QW_SZ / 4];
    else if (i < (QW_SZ + OW_SZ + F1_SZ) / 4)   v = f1[i - (QW_SZ + OW_SZ) / 4];
    else                                        v = f2[i - (QW_SZ + OW_SZ + F1_SZ) / 4];
    ushort4 o; o.x = f2b(v.x); o.y = f2b(v.y); o.z = f2b(v.z); o.w = f2b(v.w);
    dst[i] = o;
}

// ---------------- bf16 MFMA GEMM: C(MPAD,N) = A(MPAD,K) @ Bw(N,K)^T + bias ----------------
template <int BN, int RELU, int OUTBF>
__global__ __launch_bounds__(256) void gemm_mfma(
    const unsigned short* __restrict__ A,   // (MPAD,K) bf16
    const unsigned short* __restrict__ Bw,  // (N,K) bf16
    const float* __restrict__ bias,         // (N) f32
    void* __restrict__ Cout,                // (MPAD,N) f32 or bf16
    int N, int K)
{
    constexpr int NT = BN / 32;             // n-tiles per wave: 4 (BN=128) or 2 (BN=64)
    __shared__ __align__(16) unsigned short As[128 * 32];
    __shared__ __align__(16) unsigned short Bs[BN * 32];

    const int tid  = threadIdx.x;
    const int lane = tid & 63;
    const int wid  = tid >> 6;
    const int bm = blockIdx.y * 128;
    const int bn = blockIdx.x * BN;

    const int wm = (wid & 1) * 64;          // wave m-offset
    const int wn = (wid >> 1) * (BN / 2);   // wave n-offset
    const int r  = lane & 15;
    const int ko = (lane >> 4) * 8;         // k-offset (elements)

    const unsigned short* Ag = A  + (size_t)(bm + (tid >> 2)) * K + (tid & 3) * 8;
    const unsigned short* Bg = Bw + (size_t)(bn + (tid >> 2)) * K + (tid & 3) * 8;

    const bf16_8* Af = (const bf16_8*)As;
    const bf16_8* Bf = (const bf16_8*)Bs;
    int ai[4], bi[NT];
#pragma unroll
    for (int i = 0; i < 4; i++) ai[i] = ((wm + i * 16 + r) * 32 + ko) >> 3;
#pragma unroll
    for (int j = 0; j < NT; j++) bi[j] = ((wn + j * 16 + r) * 32 + ko) >> 3;

    f32x4 acc[4][NT];
#pragma unroll
    for (int i = 0; i < 4; i++)
#pragma unroll
        for (int j = 0; j < NT; j++) acc[i][j] = (f32x4){0.f, 0.f, 0.f, 0.f};

    for (int k0 = 0; k0 < K; k0 += 32) {
        __builtin_amdgcn_global_load_lds(
            (const __attribute__((address_space(1))) void*)(Ag + k0),
            (__attribute__((address_space(3))) void*)(As + tid * 8), 16, 0, 0);
        __builtin_amdgcn_global_load_lds(
            (const __attribute__((address_space(1))) void*)(Ag + (size_t)64 * K + k0),
            (__attribute__((address_space(3))) void*)(As + 2048 + tid * 8), 16, 0, 0);
        __builtin_amdgcn_global_load_lds(
            (const __attribute__((address_space(1))) void*)(Bg + k0),
            (__attribute__((address_space(3))) void*)(Bs + tid * 8), 16, 0, 0);
        if constexpr (BN == 128)
            __builtin_amdgcn_global_load_lds(
                (const __attribute__((address_space(1))) void*)(Bg + (size_t)64 * K + k0),
                (__attribute__((address_space(3))) void*)(Bs + 2048 + tid * 8), 16, 0, 0);
        __syncthreads();

        bf16_8 a[4], b[NT];
#pragma unroll
        for (int i = 0; i < 4; i++) a[i] = Af[ai[i]];
#pragma unroll
        for (int j = 0; j < NT; j++) b[j] = Bf[bi[j]];
#pragma unroll
        for (int i = 0; i < 4; i++)
#pragma unroll
            for (int j = 0; j < NT; j++)
                acc[i][j] = __builtin_amdgcn_mfma_f32_16x16x32_bf16(a[i], b[j], acc[i][j], 0, 0, 0);
        __syncthreads();
    }

    int col[NT]; float bv[NT];
#pragma unroll
    for (int j = 0; j < NT; j++) { col[j] = bn + wn + j * 16 + r; bv[j] = bias[col[j]]; }
    const int row0 = bm + wm + ((lane >> 4) << 2);
#pragma unroll
    for (int i = 0; i < 4; i++) {
#pragma unroll
        for (int rg = 0; rg < 4; rg++) {
            size_t rowoff = (size_t)(row0 + i * 16 + rg) * N;
#pragma unroll
            for (int j = 0; j < NT; j++) {
                float v = acc[i][j][rg] + bv[j];
                if (RELU) v = fmaxf(v, 0.f);
                if (OUTBF) ((unsigned short*)Cout)[rowoff + col[j]] = f2b(v);
                else       ((float*)Cout)[rowoff + col[j]] = v;
            }
        }
    }
}

// ---------------- V transpose: qkvb V-third -> Vt[bh][192][KP] bf16 (zero-padded) ----------------
__global__ __launch_bounds__(256) void vt_kernel(
    const unsigned short* __restrict__ qkv,  // (MPAD, 3H)
    unsigned short* __restrict__ vtb)        // (128, HD_, KP)
{
    __shared__ __align__(16) unsigned short Vs[KR * KLD];
    int bh = blockIdx.x;
    int b = bh >> 2, h = bh & 3;
    int tid = threadIdx.x;
    // stage V rows coalesced (rows >= LW staged as zero)
    for (int c = tid; c < KR * 24; c += 256) {
        int t = c / 24, j = c - t * 24;
        ushort8_t v = (ushort8_t){0,0,0,0,0,0,0,0};
        if (t < LW)
            v = *(const ushort8_t*)(qkv + (size_t)(b * LW + t) * (3 * H_) + 2 * H_ + h * HD_ + j * 8);
        *(ushort8_t*)(&Vs[t * KLD + j * 8]) = v;
    }
    __syncthreads();
    // write transposed, coalesced ushort4 along t
    size_t obase = (size_t)bh * (HD_ * KP);
    for (int c = tid; c < HD_ * (KP / 4); c += 256) {
        int d = c / (KP / 4), t0 = (c - d * (KP / 4)) * 4;
        ushort4 o;
        o.x = (t0 + 0 < KR) ? Vs[(t0 + 0) * KLD + d] : 0;
        o.y = (t0 + 1 < KR) ? Vs[(t0 + 1) * KLD + d] : 0;
        o.z = (t0 + 2 < KR) ? Vs[(t0 + 2) * KLD + d] : 0;
        o.w = (t0 + 3 < KR) ? Vs[(t0 + 3) * KLD + d] : 0;
        *(ushort4*)(&vtb[obase + (size_t)d * KP + t0]) = o;
    }
}

// ---------------- scores + softmax -> P[bh][TP][KP] bf16 ----------------
// grid (3, 128); each wave: one 16-row m-tile x 9 n-tiles, MFMA + in-register softmax
__global__ __launch_bounds__(256) void attn_score_kernel(
    const unsigned short* __restrict__ qkv,   // (MPAD, 3H)
    const int*            __restrict__ wvalid,
    unsigned short*       __restrict__ pb)    // (128, TP, KP)
{
    __shared__ __align__(16) unsigned short Ks[KR * KLD];
    __shared__ float msk[KR];
    int mb = blockIdx.x;          // 0..2
    int bh = blockIdx.y;
    int b = bh >> 2, h = bh & 3;
    int tid = threadIdx.x, lane = tid & 63, wid = tid >> 6;
    int q = lane >> 4, r = lane & 15;

    for (int c = tid; c < KR * 24; c += 256) {
        int t = c / 24, j = c - t * 24;
        ushort8_t v = (ushort8_t){0,0,0,0,0,0,0,0};
        if (t < LW)
            v = *(const ushort8_t*)(qkv + (size_t)(b * LW + t) * (3 * H_) + H_ + h * HD_ + j * 8);
        *(ushort8_t*)(&Ks[t * KLD + j * 8]) = v;
    }
    if (tid < KR) {
        bool valid = (tid == 0) || (tid <= W_ && wvalid[b * W_ + tid - 1] != 0);
        msk[tid] = valid ? 0.f : -1e30f;
    }
    __syncthreads();

    const int qrow0 = mb * 64 + wid * 16;   // P-row base for this wave (0..191)
    const unsigned short* Qp = qkv + ((size_t)(b * LW) + qrow0 + r) * (3 * H_) + h * HD_;

    f32x4 acc[9];
#pragma unroll
    for (int nt = 0; nt < 9; nt++) acc[nt] = (f32x4){0.f, 0.f, 0.f, 0.f};

    for (int ks = 0; ks < HD_ / 32; ks++) {
        bf16_8 a = *(const bf16_8*)(Qp + ks * 32 + q * 8);
#pragma unroll
        for (int nt = 0; nt < 9; nt++) {
            bf16_8 bfrag = *(const bf16_8*)(&Ks[(nt * 16 + r) * KLD + ks * 32 + q * 8]);
            acc[nt] = __builtin_amdgcn_mfma_f32_16x16x32_bf16(a, bfrag, acc[nt], 0, 0, 0);
        }
    }

    float mk[9];
#pragma unroll
    for (int nt = 0; nt < 9; nt++) mk[nt] = msk[nt * 16 + r];

    size_t pbase = (size_t)bh * (TP * KP);
#pragma unroll
    for (int rg = 0; rg < 4; rg++) {
        float v[9]; float mx = -1e30f;
#pragma unroll
        for (int nt = 0; nt < 9; nt++) { v[nt] = acc[nt][rg] * SCALE_ + mk[nt]; mx = fmaxf(mx, v[nt]); }
#pragma unroll
        for (int off = 1; off < 16; off <<= 1) mx = fmaxf(mx, __shfl_xor(mx, off, 64));
        float s = 0.f;
#pragma unroll
        for (int nt = 0; nt < 9; nt++) { v[nt] = __expf(v[nt] - mx); s += v[nt]; }
#pragma unroll
        for (int off = 1; off < 16; off <<= 1) s += __shfl_xor(s, off, 64);
        float inv = 1.f / s;
        int row = qrow0 + q * 4 + rg;
#pragma unroll
        for (int nt = 0; nt < 9; nt++)
            pb[pbase + (size_t)row * KP + nt * 16 + r] = f2b(v[nt] * inv);
        pb[pbase + (size_t)row * KP + KR + r] = 0;   // zero pad cols 144..159
    }
}

// ---------------- PV: ctx = P @ V  (batched MFMA, frags direct from L2) ----------------
// grid (3, 128); 4 waves = 2m x 2n; wave tile 32m x 96n; K=KP (pads are zero)
__global__ __launch_bounds__(256) void attn_pv_kernel(
    const unsigned short* __restrict__ pb,    // (128, TP, KP)
    const unsigned short* __restrict__ vtb,   // (128, HD_, KP)
    unsigned short*       __restrict__ ctx)   // (MPAD, H)
{
    int mb = blockIdx.x;
    int bh = blockIdx.y;
    int b = bh >> 2, h = bh & 3;
    int tid = threadIdx.x, lane = tid & 63, wid = tid >> 6;
    int q = lane >> 4, r = lane & 15;
    int wm = (wid & 1) * 32, wn = (wid >> 1) * 96;

    size_t pbase = (size_t)bh * (TP * KP);
    size_t vbase = (size_t)bh * (HD_ * KP);

    f32x4 acc[2][6];
#pragma unroll
    for (int i = 0; i < 2; i++)
#pragma unroll
        for (int j = 0; j < 6; j++) acc[i][j] = (f32x4){0.f, 0.f, 0.f, 0.f};

    for (int ks = 0; ks < KP / 32; ks++) {
        bf16_8 a[2], bb[6];
#pragma unroll
        for (int i = 0; i < 2; i++)
            a[i] = *(const bf16_8*)(pb + pbase + (size_t)(mb * 64 + wm + i * 16 + r) * KP + ks * 32 + q * 8);
#pragma unroll
        for (int j = 0; j < 6; j++)
            bb[j] = *(const bf16_8*)(vtb + vbase + (size_t)(wn + j * 16 + r) * KP + ks * 32 + q * 8);
#pragma unroll
        for (int i = 0; i < 2; i++)
#pragma unroll
            for (int j = 0; j < 6; j++)
                acc[i][j] = __builtin_amdgcn_mfma_f32_16x16x32_bf16(a[i], bb[j], acc[i][j], 0, 0, 0);
    }

#pragma unroll
    for (int i = 0; i < 2; i++) {
#pragma unroll
        for (int rg = 0; rg < 4; rg++) {
            int t = mb * 64 + wm + i * 16 + q * 4 + rg;
            if (t < LW) {
                size_t rowoff = (size_t)(b * LW + t) * H_ + h * HD_;
#pragma unroll
                for (int j = 0; j < 6; j++)
                    ctx[rowoff + wn + j * 16 + r] = f2b(acc[i][j][rg]);
            }
        }
    }
}

// ---------------- fused residual add + LayerNorm (x32 master, bf16 mirror) ----------------
__global__ __launch_bounds__(256) void add_ln_kernel(
    float* __restrict__ x, const float* __restrict__ res,
    const float* __restrict__ sc, const float* __restrict__ bi,
    unsigned short* __restrict__ xb)
{
    __shared__ float red[4];
    int row = blockIdx.x;
    int tid = threadIdx.x;
    size_t base = (size_t)row * H_;
    float v[3];
    float sum = 0.f;
#pragma unroll
    for (int i = 0; i < 3; i++) {
        int c = tid + i * 256;
        float t = x[base + c] + res[base + c];
        v[i] = t; sum += t;
    }
    sum = block_sum(sum, red);
    float mean = sum * (1.f / H_);
    float var = 0.f;
#pragma unroll
    for (int i = 0; i < 3; i++) { float d = v[i] - mean; var += d * d; }
    var = block_sum(var, red);
    float inv = rsqrtf(var * (1.f / H_) + EPS_);
#pragma unroll
    for (int i = 0; i < 3; i++) {
        int c = tid + i * 256;
        float r = (v[i] - mean) * inv * sc[c] + bi[c];
        x[base + c] = r;
        xb[base + c] = f2b(r);
    }
}

// ---------------- classifier + pooled copy (pure fp32) ----------------
__global__ __launch_bounds__(256) void cls_kernel(
    const float* __restrict__ x,
    const float* __restrict__ cls_w, const float* __restrict__ cls_b,
    float* __restrict__ out)
{
    int tid = threadIdx.x;
    for (int i = tid; i < B_ * H_; i += 256) {
        int b = i / H_, c = i % H_;
        out[B_ * NLAB_ + i] = x[((size_t)b * LW) * H_ + c];
    }
    if (tid < B_ * NLAB_) {
        int b = tid / NLAB_, lab = tid % NLAB_;
        float acc = cls_b[lab];
        const float* p = &x[((size_t)b * LW) * H_];
        const float* wv = &cls_w[lab * H_];
        for (int c = 0; c < H_; c++) acc += p[c] * wv[c];
        out[b * NLAB_ + lab] = acc;
    }
}

extern "C" void kernel_launch(void* const* d_in, const int* in_sizes, int n_in,
                              void* d_out, int out_size, void* d_ws, size_t ws_size,
                              hipStream_t stream) {
    const float* hidden = (const float*)d_in[0];
    const int*   wti    = (const int*)d_in[1];
    const int*   gmask  = (const int*)d_in[2];
    const int*   wvalid = (const int*)d_in[3];
    const float* qkv_w  = (const float*)d_in[4];
    const float* qkv_b  = (const float*)d_in[5];
    const float* out_w  = (const float*)d_in[6];
    const float* out_b  = (const float*)d_in[7];
    const float* ff1_w  = (const float*)d_in[8];
    const float* ff1_b  = (const float*)d_in[9];
    const float* ff2_w  = (const float*)d_in[10];
    const float* ff2_b  = (const float*)d_in[11];
    const float* ln1_s  = (const float*)d_in[12];
    const float* ln1_b  = (const float*)d_in[13];
    const float* ln2_s  = (const float*)d_in[14];
    const float* ln2_b  = (const float*)d_in[15];
    const float* cls_w  = (const float*)d_in[16];
    const float* cls_b  = (const float*)d_in[17];
    float* out = (float*)d_out;

    // workspace: 72.2 MB (proven >= 76.1 MB available in R1)
    const size_t XSZ = (size_t)MPAD * H_;             // 3,244,032
    const size_t ASZ = (size_t)128 * TP * KP;         // 3,932,160 (pb; vtb is 128*HD_*KP = 3,932,160 too... HD_*KP=30720, *128 = 3,932,160)
    float* x32   = (float*)d_ws;                      // XSZ f32
    float* tmp32 = x32 + XSZ;                         // scratch region: max(XSZ f32, 2*ASZ bf16) = ASZ f32s
    unsigned short* vtb = (unsigned short*)tmp32;     // ASZ bf16 (aliases tmp32)
    unsigned short* pb  = vtb + ASZ;                  // ASZ bf16 (aliases tmp32)
    unsigned short* xb   = (unsigned short*)(tmp32 + ASZ);   // XSZ bf16
    unsigned short* ctxb = xb + XSZ;                  // XSZ bf16
    unsigned short* qkvb = ctxb + XSZ;                // MPAD*3H bf16 (aliased: h1b MPAD*FF)
    unsigned short* wb   = qkvb + (size_t)MPAD * 3 * H_;     // WL_SZ bf16

    build_x_kernel<<<dim3(LW, B_), 256, 0, stream>>>(hidden, wti, gmask, wvalid, x32, xb);
    zero_pad_xb<<<288, 256, 0, stream>>>(xb);

    for (int l = 0; l < NL_; l++) {
        cvt_layer_kernel<<<WL_SZ / 4 / 256, 256, 0, stream>>>(
            (const float4*)(qkv_w + (size_t)l * QW_SZ), (const float4*)(out_w + (size_t)l * OW_SZ),
            (const float4*)(ff1_w + (size_t)l * F1_SZ), (const float4*)(ff2_w + (size_t)l * F2_SZ),
            (ushort4*)wb);
        // qkv = x @ qkv_w^T + b  -> bf16
        gemm_mfma<128, 0, 1><<<dim3(3 * H_ / 128, MPAD / 128), 256, 0, stream>>>(
            xb, wb, qkv_b + (size_t)l * 3 * H_, qkvb, 3 * H_, H_);
        // attention: V-transpose, scores+softmax, PV
        vt_kernel<<<128, 256, 0, stream>>>(qkvb, vtb);
        attn_score_kernel<<<dim3(3, 128), 256, 0, stream>>>(qkvb, wvalid, pb);
        attn_pv_kernel<<<dim3(3, 128), 256, 0, stream>>>(pb, vtb, ctxb);
        // attn out-proj -> f32 tmp (overwrites vtb/pb region — no longer needed)
        gemm_mfma<64, 0, 0><<<dim3(H_ / 64, MPAD / 128), 256, 0, stream>>>(
            ctxb, wb + QW_SZ, out_b + (size_t)l * H_, tmp32, H_, H_);
        add_ln_kernel<<<M_, 256, 0, stream>>>(x32, tmp32,
            ln1_s + (size_t)l * H_, ln1_b + (size_t)l * H_, xb);
        // h1 = relu(x @ ff1_w^T + b) -> bf16 (into qkvb region)
        gemm_mfma<128, 1, 1><<<dim3(FF_ / 128, MPAD / 128), 256, 0, stream>>>(
            xb, wb + QW_SZ + OW_SZ, ff1_b + (size_t)l * FF_, qkvb, FF_, H_);
        // ff2 -> f32 tmp
        gemm_mfma<64, 0, 0><<<dim3(H_ / 64, MPAD / 128), 256, 0, stream>>>(
            qkvb, wb + QW_SZ + OW_SZ + F1_SZ, ff2_b + (size_t)l * H_, tmp32, H_, FF_);
        add_ln_kernel<<<M_, 256, 0, stream>>>(x32, tmp32,
            ln2_s + (size_t)l * H_, ln2_b + (size_t)l * H_, xb);
    }
    cls_kernel<<<1, 256, 0, stream>>>(x32, cls_w, cls_b, out);
    (void)in_sizes; (void)n_in; (void)out_size; (void)ws_size;
}